// Round 7
// baseline (414.203 us; speedup 1.0000x reference)
//
#include <hip/hip_runtime.h>
#include <hip/hip_fp16.h>

#define N_NODES    100000
#define N_EDGES    3200000
#define HIDDEN     64
#define NUM_GRAPHS 128
#define NUM_LABELS 1000

#define BKT_SHIFT  8
#define NPB        256                              // nodes per bucket
#define NBKT       ((N_NODES + NPB - 1) / NPB)      // 391
#define ENTCAP     8960                             // LDS staging capacity (71.7 KB)
#define BSLOT      ENTCAP                           // fixed bucket slot capacity
                                                    // mean bucket = 8192, sd = 90.4 -> 8960 is +8.5 sigma
#define SCHUNK     4096                             // edges per scatter block
#define SNBLK      ((N_EDGES + SCHUNK - 1) / SCHUNK)  // 782
#define CPT        ((SNBLK + 255) / 256)            // 4 blocks per thread in column scan

// ---------------- K1: per-block bucket histogram -> cnt[blk][NBKT] ----------------
__global__ __launch_bounds__(256) void hist_blk_kernel(
    const int* __restrict__ dst, int* __restrict__ cnt, int E) {
    __shared__ int h[NBKT];
    int t = threadIdx.x;
    for (int b = t; b < NBKT; b += 256) h[b] = 0;
    __syncthreads();
    int base = blockIdx.x * SCHUNK;
    int end  = min(base + SCHUNK, E);
    for (int i = base + t; i < end; i += 256)
        atomicAdd(&h[dst[i] >> BKT_SHIFT], 1);
    __syncthreads();
    int* o = cnt + (size_t)blockIdx.x * NBKT;
    for (int b = t; b < NBKT; b += 256) o[b] = h[b];
}

// ---------------- K2: per-bucket exclusive scan over blocks ----------------
// basem[blk][b] = sum_{blk'<blk} cnt[blk'][b];  bktTot[b] = total.
__global__ __launch_bounds__(256) void scan_cols_kernel(
    const int* __restrict__ cnt, int* __restrict__ basem, int* __restrict__ bktTot) {
    __shared__ int a[256], bsh[256];
    int b = blockIdx.x;
    int t = threadIdx.x;
    int v[CPT];
    int loc = 0;
    int blk0 = t * CPT;
    #pragma unroll
    for (int j = 0; j < CPT; ++j) {
        int blk = blk0 + j;
        int c = (blk < SNBLK) ? cnt[(size_t)blk * NBKT + b] : 0;
        v[j] = loc;                       // local exclusive prefix
        loc += c;
    }
    a[t] = loc; __syncthreads();
    int* pa = a; int* pb = bsh;
    #pragma unroll
    for (int d = 1; d < 256; d <<= 1) {
        int x = pa[t];
        if (t >= d) x += pa[t - d];
        pb[t] = x; __syncthreads();
        int* tmp = pa; pa = pb; pb = tmp;
    }
    int ex = (t == 0) ? 0 : pa[t - 1];
    #pragma unroll
    for (int j = 0; j < CPT; ++j) {
        int blk = blk0 + j;
        if (blk < SNBLK) basem[(size_t)blk * NBKT + b] = ex + v[j];
    }
    if (t == 255) bktTot[b] = pa[255];
}

// ---------------- K3: scan bucket totals -> dense offsets ----------------
__global__ __launch_bounds__(512) void scan_buckets_kernel(const int* __restrict__ bktTot,
                                                           int* __restrict__ boff) {
    __shared__ int a[512], b[512];
    int t = threadIdx.x;
    int v = (t < NBKT) ? bktTot[t] : 0;
    a[t] = v; __syncthreads();
    int* pa = a; int* pb = b;
    #pragma unroll
    for (int d = 1; d < 512; d <<= 1) {
        int x = pa[t];
        if (t >= d) x += pa[t - d];
        pb[t] = x; __syncthreads();
        int* tmp = pa; pa = pb; pb = tmp;
    }
    int ex = (t == 0) ? 0 : pa[t - 1];
    if (t < NBKT) boff[t] = ex;
    if (t == NBKT - 1) boff[NBKT] = pa[t];
}

// ---------------- K4: LDS-staged scatter (no global atomics, coalesced runs) ----------------
// barr entry: x = src | (dstoff << 20), y = bits(ew)
// Loads its own cnt row (no recount), groups entries by bucket in LDS, streams out.
__global__ __launch_bounds__(256) void scatter_kernel(
    const int* __restrict__ src, const int* __restrict__ dst,
    const float* __restrict__ ew, const int* __restrict__ cnt,
    const int* __restrict__ basem, int2* __restrict__ barr, int E) {
    __shared__ int2 ent[SCHUNK];      // 32 KB: bucket-grouped entries
    __shared__ int  gaddr[SCHUNK];    // 16 KB: final slot per staged entry
    __shared__ int  h[NBKT];          // running cursor per bucket
    __shared__ int  ls[NBKT];         // local bucket start
    __shared__ int  a[256], bsc[256];
    int t = threadIdx.x;
    int blk = blockIdx.x;
    const int* cn = cnt   + (size_t)blk * NBKT;
    const int* bm = basem + (size_t)blk * NBKT;
    // scan cnt row (2 elems/thread) -> ls; zero cursors
    int i0 = 2 * t, i1 = 2 * t + 1;
    int c0 = (i0 < NBKT) ? cn[i0] : 0;
    int c1 = (i1 < NBKT) ? cn[i1] : 0;
    a[t] = c0 + c1; __syncthreads();
    int* pa = a; int* pb = bsc;
    #pragma unroll
    for (int d = 1; d < 256; d <<= 1) {
        int x = pa[t];
        if (t >= d) x += pa[t - d];
        pb[t] = x; __syncthreads();
        int* tmp = pa; pa = pb; pb = tmp;
    }
    int ex = (t == 0) ? 0 : pa[t - 1];
    if (i0 < NBKT) { ls[i0] = ex;      h[i0] = 0; }
    if (i1 < NBKT) { ls[i1] = ex + c0; h[i1] = 0; }
    __syncthreads();
    int base = blk * SCHUNK;
    int end  = min(base + SCHUNK, E);
    int m    = end - base;
    for (int i = base + t; i < end; i += 256) {
        int d  = dst[i];
        int bk = d >> BKT_SHIFT;
        int p  = atomicAdd(&h[bk], 1);
        int j  = ls[bk] + p;
        ent[j]   = make_int2(src[i] | ((d & (NPB - 1)) << 20), __float_as_int(ew[i]));
        gaddr[j] = bk * BSLOT + bm[bk] + p;
    }
    __syncthreads();
    for (int j = t; j < m; j += 256) barr[gaddr[j]] = ent[j];
}

// ---------------- K5: per-bucket dinv (needed before finalize folds dinv[src]) ----------------
__global__ __launch_bounds__(256) void dinv_bucket_kernel(
    const int2* __restrict__ barr, const int* __restrict__ bktTot,
    float* __restrict__ dinv) {
    __shared__ float wsum[NPB];
    int b = blockIdx.x, t = threadIdx.x;
    wsum[t] = 0.f;
    __syncthreads();
    int m = bktTot[b];
    const int2* bs = barr + (size_t)b * BSLOT;
    for (int i = t; i < m; i += 256) {
        int2 v = bs[i];
        atomicAdd(&wsum[(v.x >> 20) & (NPB - 1)], __int_as_float(v.y));
    }
    __syncthreads();
    int node = (b << BKT_SHIFT) + t;
    if (node < N_NODES) dinv[node] = rsqrtf(wsum[t] + 1.0f);
}

// ---------------- K6: merged per-bucket finalize -> off + CSR ----------------
// csr entry: x = src | (labels[src] << 17), y = bits(ew * dinv[dst] * dinv[src])
__global__ __launch_bounds__(256) void finalize_kernel(
    const int2* __restrict__ barr, const int* __restrict__ boff,
    const int* __restrict__ labels, const float* __restrict__ dinv,
    int2* __restrict__ csr, int* __restrict__ off) {
    __shared__ int2  ent[ENTCAP];
    __shared__ int   hcnt[NPB];
    __shared__ float ldv[NPB];
    __shared__ int   ha[NPB], hcur[NPB];
    int b = blockIdx.x;
    int t = threadIdx.x;
    int s = boff[b], e = boff[b + 1];
    int m = e - s;
    const int2* bsrc = barr + (size_t)b * BSLOT;
    int node0 = b << BKT_SHIFT;
    int nn = min(NPB, N_NODES - node0);
    hcnt[t] = 0;
    ldv[t]  = (t < nn) ? dinv[node0 + t] : 0.f;
    __syncthreads();
    bool staged = (m <= ENTCAP);      // always true by construction
    for (int i = t; i < m; i += 256) {
        int2 v = bsrc[i];
        if (staged) ent[i] = v;
        atomicAdd(&hcnt[(v.x >> 20) & (NPB - 1)], 1);
    }
    __syncthreads();
    ha[t] = hcnt[t];
    __syncthreads();
    #pragma unroll
    for (int d = 1; d < NPB; d <<= 1) {
        int x = ha[t];
        if (t >= d) x += ha[t - d];
        __syncthreads();
        ha[t] = x;
        __syncthreads();
    }
    {
        int ex = (t == 0) ? 0 : ha[t - 1];
        hcur[t] = s + ex;
        if (t < nn) off[node0 + t] = s + ex;
    }
    if (b == NBKT - 1 && t == 0) off[N_NODES] = e;
    __syncthreads();
    for (int i = t; i < m; i += 256) {
        int2 v = staged ? ent[i] : bsrc[i];
        int doff = (v.x >> 20) & (NPB - 1);
        int sv   = v.x & 0xFFFFF;                      // src (17 bits used)
        float wf = __int_as_float(v.y) * ldv[doff] * dinv[sv];  // full norm folded
        int lab  = labels[sv];
        int p = atomicAdd(&hcur[doff], 1);
        csr[p] = make_int2(sv | (lab << 17), __float_as_int(wf));
    }
}

// ---------------- EW1 = emb @ W1 (1000x64), fp16 out ----------------
__global__ __launch_bounds__(256) void ew1_kernel(
    const float* __restrict__ emb, const float* __restrict__ W,
    __half* __restrict__ OUTH) {
    __shared__ float Ws[64 * 64];
    __shared__ float Xs[64 * 65];
    int t = threadIdx.x;
    #pragma unroll
    for (int s = 0; s < 16; ++s) Ws[s * 256 + t] = W[s * 256 + t];
    int r0   = blockIdx.x * 64;
    int lrow = t >> 2;
    int c0   = (t & 3) * 16;
    int grow = r0 + lrow;
    const float* srcrow = (grow < NUM_LABELS) ? (emb + (size_t)grow * HIDDEN) : emb;
    #pragma unroll
    for (int c = 0; c < 16; c += 4) {
        float4 v = *(const float4*)(srcrow + c0 + c);
        Xs[lrow * 65 + c0 + c + 0] = v.x;
        Xs[lrow * 65 + c0 + c + 1] = v.y;
        Xs[lrow * 65 + c0 + c + 2] = v.z;
        Xs[lrow * 65 + c0 + c + 3] = v.w;
    }
    __syncthreads();
    int row = t & 63;
    int j0  = (t >> 6) * 16;
    float4 a0 = make_float4(0,0,0,0), a1 = a0, a2 = a0, a3 = a0;
    #pragma unroll
    for (int k = 0; k < 64; ++k) {
        float xv = Xs[row * 65 + k];
        const float4* wr = (const float4*)(Ws + k * 64 + j0);
        float4 w0 = wr[0], w1 = wr[1], w2 = wr[2], w3 = wr[3];
        a0.x = fmaf(xv, w0.x, a0.x); a0.y = fmaf(xv, w0.y, a0.y);
        a0.z = fmaf(xv, w0.z, a0.z); a0.w = fmaf(xv, w0.w, a0.w);
        a1.x = fmaf(xv, w1.x, a1.x); a1.y = fmaf(xv, w1.y, a1.y);
        a1.z = fmaf(xv, w1.z, a1.z); a1.w = fmaf(xv, w1.w, a1.w);
        a2.x = fmaf(xv, w2.x, a2.x); a2.y = fmaf(xv, w2.y, a2.y);
        a2.z = fmaf(xv, w2.z, a2.z); a2.w = fmaf(xv, w2.w, a2.w);
        a3.x = fmaf(xv, w3.x, a3.x); a3.y = fmaf(xv, w3.y, a3.y);
        a3.z = fmaf(xv, w3.z, a3.z); a3.w = fmaf(xv, w3.w, a3.w);
    }
    int gr = r0 + row;
    if (gr < NUM_LABELS) {
        union { __half2 h2[8]; uint4 u4[2]; } pk;
        pk.h2[0] = __floats2half2_rn(a0.x, a0.y);
        pk.h2[1] = __floats2half2_rn(a0.z, a0.w);
        pk.h2[2] = __floats2half2_rn(a1.x, a1.y);
        pk.h2[3] = __floats2half2_rn(a1.z, a1.w);
        pk.h2[4] = __floats2half2_rn(a2.x, a2.y);
        pk.h2[5] = __floats2half2_rn(a2.z, a2.w);
        pk.h2[6] = __floats2half2_rn(a3.x, a3.y);
        pk.h2[7] = __floats2half2_rn(a3.z, a3.w);
        uint4* o = (uint4*)(OUTH + (size_t)gr * HIDDEN + j0);
        o[0] = pk.u4[0]; o[1] = pk.u4[1];
    }
}

// 8 fp16 features -> fp32 acc, scalar weight.
// NOTE: macro params must not be named x/y/z/w (token-pasted into member access).
#define ACC8(rv_, wv_) { \
    const __half2* hp_ = (const __half2*)&(rv_); \
    float2 f0_ = __half22float2(hp_[0]); \
    float2 f1_ = __half22float2(hp_[1]); \
    float2 f2_ = __half22float2(hp_[2]); \
    float2 f3_ = __half22float2(hp_[3]); \
    accA.x = fmaf(f0_.x, (wv_), accA.x); accA.y = fmaf(f0_.y, (wv_), accA.y); \
    accA.z = fmaf(f1_.x, (wv_), accA.z); accA.w = fmaf(f1_.y, (wv_), accA.w); \
    accB.x = fmaf(f2_.x, (wv_), accB.x); accB.y = fmaf(f2_.y, (wv_), accB.y); \
    accB.z = fmaf(f3_.x, (wv_), accB.z); accB.w = fmaf(f3_.y, (wv_), accB.w); }

#define RED8(of_) { \
    accA.x += __shfl_xor(accA.x, of_, 64); accA.y += __shfl_xor(accA.y, of_, 64); \
    accA.z += __shfl_xor(accA.z, of_, 64); accA.w += __shfl_xor(accA.w, of_, 64); \
    accB.x += __shfl_xor(accB.x, of_, 64); accB.y += __shfl_xor(accB.y, of_, 64); \
    accB.z += __shfl_xor(accB.z, of_, 64); accB.w += __shfl_xor(accB.w, of_, 64); }

// ---------------- conv1: agg over EW1[label] -> A1 = relu(acc + di2*self + b1), fp16 out ----------------
// wave per node; 8 lanes/edge (uint4 = 8 halves); 4 independent edge-chains in flight.
// Edge weight fully folded in csr.y — no per-edge dinv lookup.
__global__ __launch_bounds__(256) void agg1_kernel(
    const __half* __restrict__ EW1h, const int* __restrict__ labels,
    const int2* __restrict__ csr, const int* __restrict__ off,
    const float* __restrict__ dinv, const float* __restrict__ bias,
    __half* __restrict__ A1h, int n) {
    int wid  = (blockIdx.x * blockDim.x + threadIdx.x) >> 6;
    if (wid >= n) return;
    int lane = threadIdx.x & 63;
    int q = lane & 7, g = lane >> 3;
    int i   = off[wid] + g;
    int end = off[wid + 1];
    float4 accA = make_float4(0.f,0.f,0.f,0.f), accB = accA;
    while (i < end) {
        int2 e0 = csr[i];
        int2 e1 = (i + 8  < end) ? csr[i + 8]  : make_int2(0, 0);
        int2 e2 = (i + 16 < end) ? csr[i + 16] : make_int2(0, 0);
        int2 e3 = (i + 24 < end) ? csr[i + 24] : make_int2(0, 0);
        uint4 r0 = *(const uint4*)(EW1h + (size_t)((unsigned)e0.x >> 17) * HIDDEN + q * 8);
        uint4 r1 = *(const uint4*)(EW1h + (size_t)((unsigned)e1.x >> 17) * HIDDEN + q * 8);
        uint4 r2 = *(const uint4*)(EW1h + (size_t)((unsigned)e2.x >> 17) * HIDDEN + q * 8);
        uint4 r3 = *(const uint4*)(EW1h + (size_t)((unsigned)e3.x >> 17) * HIDDEN + q * 8);
        float w0 = __int_as_float(e0.y);
        float w1 = __int_as_float(e1.y);
        float w2 = __int_as_float(e2.y);
        float w3 = __int_as_float(e3.y);
        ACC8(r0, w0); ACC8(r1, w1); ACC8(r2, w2); ACC8(r3, w3);
        i += 32;
    }
    RED8(8); RED8(16); RED8(32);
    if (g == 0) {
        float di  = dinv[wid];
        float di2 = di * di;
        int labw = labels[wid];
        uint4 xu = *(const uint4*)(EW1h + (size_t)labw * HIDDEN + q * 8);
        const __half2* xp = (const __half2*)&xu;
        float2 x0 = __half22float2(xp[0]);
        float2 x1 = __half22float2(xp[1]);
        float2 x2 = __half22float2(xp[2]);
        float2 x3 = __half22float2(xp[3]);
        const float4* bp = (const float4*)(bias + q * 8);
        float4 bv0 = bp[0], bv1 = bp[1];
        float4 vA, vB;
        vA.x = fmaxf(fmaf(x0.x, di2, accA.x) + bv0.x, 0.f);
        vA.y = fmaxf(fmaf(x0.y, di2, accA.y) + bv0.y, 0.f);
        vA.z = fmaxf(fmaf(x1.x, di2, accA.z) + bv0.z, 0.f);
        vA.w = fmaxf(fmaf(x1.y, di2, accA.w) + bv0.w, 0.f);
        vB.x = fmaxf(fmaf(x2.x, di2, accB.x) + bv1.x, 0.f);
        vB.y = fmaxf(fmaf(x2.y, di2, accB.y) + bv1.y, 0.f);
        vB.z = fmaxf(fmaf(x3.x, di2, accB.z) + bv1.z, 0.f);
        vB.w = fmaxf(fmaf(x3.y, di2, accB.w) + bv1.w, 0.f);
        union { __half2 h2[4]; uint4 u4; } pk;
        pk.h2[0] = __floats2half2_rn(vA.x, vA.y);
        pk.h2[1] = __floats2half2_rn(vA.z, vA.w);
        pk.h2[2] = __floats2half2_rn(vB.x, vB.y);
        pk.h2[3] = __floats2half2_rn(vB.z, vB.w);
        *(uint4*)(A1h + (size_t)wid * HIDDEN + q * 8) = pk.u4;
    }
}

// ---------------- conv2 pull aggregation (fp16 activation gather) -> fp32 out ----------------
__global__ __launch_bounds__(256) void agg2_kernel(
    const __half* __restrict__ Xh,
    const int2* __restrict__ csr, const int* __restrict__ off,
    const float* __restrict__ dinv, float* __restrict__ OUT, int n) {
    int wid  = (blockIdx.x * blockDim.x + threadIdx.x) >> 6;
    if (wid >= n) return;
    int lane = threadIdx.x & 63;
    int q = lane & 7, g = lane >> 3;
    int i   = off[wid] + g;
    int end = off[wid + 1];
    float4 accA = make_float4(0.f,0.f,0.f,0.f), accB = accA;
    while (i < end) {
        int2 e0 = csr[i];
        int2 e1 = (i + 8  < end) ? csr[i + 8]  : make_int2(0, 0);
        int2 e2 = (i + 16 < end) ? csr[i + 16] : make_int2(0, 0);
        int2 e3 = (i + 24 < end) ? csr[i + 24] : make_int2(0, 0);
        uint4 r0 = *(const uint4*)(Xh + (size_t)(e0.x & 0x1FFFF) * HIDDEN + q * 8);
        uint4 r1 = *(const uint4*)(Xh + (size_t)(e1.x & 0x1FFFF) * HIDDEN + q * 8);
        uint4 r2 = *(const uint4*)(Xh + (size_t)(e2.x & 0x1FFFF) * HIDDEN + q * 8);
        uint4 r3 = *(const uint4*)(Xh + (size_t)(e3.x & 0x1FFFF) * HIDDEN + q * 8);
        float w0 = __int_as_float(e0.y);
        float w1 = __int_as_float(e1.y);
        float w2 = __int_as_float(e2.y);
        float w3 = __int_as_float(e3.y);
        ACC8(r0, w0); ACC8(r1, w1); ACC8(r2, w2); ACC8(r3, w3);
        i += 32;
    }
    RED8(8); RED8(16); RED8(32);
    if (g == 0) {
        float di  = dinv[wid];
        float di2 = di * di;
        uint4 xu = *(const uint4*)(Xh + (size_t)wid * HIDDEN + q * 8);
        const __half2* xp = (const __half2*)&xu;
        float2 x0 = __half22float2(xp[0]);
        float2 x1 = __half22float2(xp[1]);
        float2 x2 = __half22float2(xp[2]);
        float2 x3 = __half22float2(xp[3]);
        accA.x = fmaf(x0.x, di2, accA.x);
        accA.y = fmaf(x0.y, di2, accA.y);
        accA.z = fmaf(x1.x, di2, accA.z);
        accA.w = fmaf(x1.y, di2, accA.w);
        accB.x = fmaf(x2.x, di2, accB.x);
        accB.y = fmaf(x2.y, di2, accB.y);
        accB.z = fmaf(x3.x, di2, accB.z);
        accB.w = fmaf(x3.y, di2, accB.w);
        float* o = OUT + (size_t)wid * HIDDEN + q * 8;
        *(float4*)o       = accA;
        *(float4*)(o + 4) = accB;
    }
}

// ---------------- GEMM + bias + relu -> fp32 out (plain stores, NO atomics) ----------------
__global__ __launch_bounds__(256) void gemm2_kernel(
    const float* __restrict__ X, const float* __restrict__ W,
    const float* __restrict__ bias, float* __restrict__ OUT, int n) {
    __shared__ float Ws[64 * 64];
    __shared__ float Xs[64 * 65];
    int t = threadIdx.x;
    #pragma unroll
    for (int s = 0; s < 16; ++s) Ws[s * 256 + t] = W[s * 256 + t];
    int r0   = blockIdx.x * 64;
    int lrow = t >> 2;
    int c0   = (t & 3) * 16;
    const float* srcrow = ((r0 + lrow) < n) ? (X + (size_t)(r0 + lrow) * HIDDEN) : X;
    #pragma unroll
    for (int c = 0; c < 16; c += 4) {
        float4 v = *(const float4*)(srcrow + c0 + c);
        Xs[lrow * 65 + c0 + c + 0] = v.x;
        Xs[lrow * 65 + c0 + c + 1] = v.y;
        Xs[lrow * 65 + c0 + c + 2] = v.z;
        Xs[lrow * 65 + c0 + c + 3] = v.w;
    }
    __syncthreads();
    int row = t & 63;
    int j0  = (t >> 6) * 16;
    float4 a0 = *(const float4*)(bias + j0 + 0);
    float4 a1 = *(const float4*)(bias + j0 + 4);
    float4 a2 = *(const float4*)(bias + j0 + 8);
    float4 a3 = *(const float4*)(bias + j0 + 12);
    #pragma unroll
    for (int k = 0; k < 64; ++k) {
        float xv = Xs[row * 65 + k];
        const float4* wr = (const float4*)(Ws + k * 64 + j0);
        float4 w0 = wr[0], w1 = wr[1], w2 = wr[2], w3 = wr[3];
        a0.x = fmaf(xv, w0.x, a0.x); a0.y = fmaf(xv, w0.y, a0.y);
        a0.z = fmaf(xv, w0.z, a0.z); a0.w = fmaf(xv, w0.w, a0.w);
        a1.x = fmaf(xv, w1.x, a1.x); a1.y = fmaf(xv, w1.y, a1.y);
        a1.z = fmaf(xv, w1.z, a1.z); a1.w = fmaf(xv, w1.w, a1.w);
        a2.x = fmaf(xv, w2.x, a2.x); a2.y = fmaf(xv, w2.y, a2.y);
        a2.z = fmaf(xv, w2.z, a2.z); a2.w = fmaf(xv, w2.w, a2.w);
        a3.x = fmaf(xv, w3.x, a3.x); a3.y = fmaf(xv, w3.y, a3.y);
        a3.z = fmaf(xv, w3.z, a3.z); a3.w = fmaf(xv, w3.w, a3.w);
    }
    int gr = r0 + row;
    if (gr < n) {
        float4* o = (float4*)(OUT + (size_t)gr * HIDDEN + j0);
        a0.x = fmaxf(a0.x, 0.f); a0.y = fmaxf(a0.y, 0.f); a0.z = fmaxf(a0.z, 0.f); a0.w = fmaxf(a0.w, 0.f);
        a1.x = fmaxf(a1.x, 0.f); a1.y = fmaxf(a1.y, 0.f); a1.z = fmaxf(a1.z, 0.f); a1.w = fmaxf(a1.w, 0.f);
        a2.x = fmaxf(a2.x, 0.f); a2.y = fmaxf(a2.y, 0.f); a2.z = fmaxf(a2.z, 0.f); a2.w = fmaxf(a2.w, 0.f);
        a3.x = fmaxf(a3.x, 0.f); a3.y = fmaxf(a3.y, 0.f); a3.z = fmaxf(a3.z, 0.f); a3.w = fmaxf(a3.w, 0.f);
        o[0] = a0; o[1] = a1; o[2] = a2; o[3] = a3;
    }
}

// ---------------- fused mean-pool (binary search on sorted batch) + MLP head ----------------
__global__ __launch_bounds__(256) void pool_head_kernel(
    const float* __restrict__ A, const int* __restrict__ batch,
    const float* __restrict__ W3, const float* __restrict__ b3,
    const float* __restrict__ W4, const float* __restrict__ b4,
    float* __restrict__ out) {
    __shared__ int   sb[2];
    __shared__ float sd[4][64];
    __shared__ float gv[64];
    int gidx = blockIdx.x;
    int t = threadIdx.x;
    if (t < 2) {
        int target = gidx + t;
        int lo = 0, hi = N_NODES;
        while (lo < hi) {
            int mid = (lo + hi) >> 1;
            if (batch[mid] < target) lo = mid + 1; else hi = mid;
        }
        sb[t] = lo;
    }
    __syncthreads();
    int start = sb[0], end = sb[1];
    int col = t & 63, rg = t >> 6;
    float sum = 0.f;
    for (int r = start + rg; r < end; r += 4) sum += A[(size_t)r * HIDDEN + col];
    sd[rg][col] = sum;
    __syncthreads();
    if (t < 64) {
        float tot = sd[0][col] + sd[1][col] + sd[2][col] + sd[3][col];
        float cnt = (float)(end - start);
        gv[col] = tot / fmaxf(cnt, 1.0f);
    }
    __syncthreads();
    if (t < 64) {
        float acc = b3[t];
        #pragma unroll
        for (int k = 0; k < 64; ++k) acc = fmaf(gv[k], W3[k * 64 + t], acc);
        float p = fmaxf(acc, 0.f) * W4[t];
        #pragma unroll
        for (int o = 32; o > 0; o >>= 1) p += __shfl_down(p, o, 64);
        if (t == 0) out[gidx] = p + b4[0];
    }
}

extern "C" void kernel_launch(void* const* d_in, const int* in_sizes, int n_in,
                              void* d_out, int out_size, void* d_ws, size_t ws_size,
                              hipStream_t stream) {
    const int*   labels = (const int*)d_in[0];
    const int*   ei     = (const int*)d_in[1];
    const int*   src    = ei;
    const int*   dst    = ei + N_EDGES;
    const float* ew     = (const float*)d_in[2];
    const int*   batch  = (const int*)d_in[3];
    const float* emb    = (const float*)d_in[4];
    const float* W1 = (const float*)d_in[5],  *b1 = (const float*)d_in[6];
    const float* W2 = (const float*)d_in[7],  *b2 = (const float*)d_in[8];
    const float* W3 = (const float*)d_in[9],  *b3 = (const float*)d_in[10];
    const float* W4 = (const float*)d_in[11], *b4 = (const float*)d_in[12];
    float* out = (float*)d_out;

    // workspace carve
    float* ws   = (float*)d_ws;
    float* bufH = ws;                                       // N*64 fp32 (agg2 out / gemm2 in)
    float* bufA = bufH + (size_t)N_NODES * HIDDEN;          // N*64 fp32 region: A1h (fp16) -> A2 (fp32)
    int2*  csr  = (int2*)(bufA + (size_t)N_NODES * HIDDEN); // E int2
    int*   boff   = (int*)(csr + N_EDGES);                  // NBKT+1
    int*   bktTot = boff + NBKT + 1;                        // NBKT (bucket totals from scan_cols)
    int*   off    = bktTot + NBKT;                          // N+1
    float* dinv   = (float*)(off + N_NODES + 1);            // N
    __half* EW1h  = (__half*)(dinv + N_NODES);              // 1000*64 fp16
    // barr: fixed-slot bucket buffer, 391*8960*8B = 28.0 MB.
    // Aliases bufH (25.6 MB) + first 2.4 MB of bufA — both dead until after finalize.
    int2*  barr   = (int2*)ws;
    __half* A1h   = (__half*)bufA;                          // fp16 activation, after finalize
    float* A2     = bufA;                                   // fp32 conv2 out (A1h dead after agg2)
    // cnt/basem: per-(block,bucket) counts & bases, 2 x 782*391*4B = 2.44 MB.
    // Alias the csr region (csr written only in finalize, after cnt/basem are dead).
    int*   cnt    = (int*)csr;                              // SNBLK*NBKT
    int*   basem  = cnt + (size_t)SNBLK * NBKT;             // SNBLK*NBKT

    const int NT = 256;
    const int blkW = (N_NODES * 64 + NT - 1) / NT;          // wave per node
    const int blkG = (N_NODES + 63) / 64;

    // ---- CSR build: radix-partition, zero global atomics, LDS-staged writeout ----
    hist_blk_kernel<<<SNBLK, NT, 0, stream>>>(dst, cnt, N_EDGES);
    scan_cols_kernel<<<NBKT, NT, 0, stream>>>(cnt, basem, bktTot);
    scan_buckets_kernel<<<1, 512, 0, stream>>>(bktTot, boff);
    scatter_kernel<<<SNBLK, NT, 0, stream>>>(src, dst, ew, cnt, basem, barr, N_EDGES);
    dinv_bucket_kernel<<<NBKT, NT, 0, stream>>>(barr, bktTot, dinv);
    finalize_kernel<<<NBKT, NT, 0, stream>>>(barr, boff, labels, dinv, csr, off);

    // ---- conv1: EW1 = emb@W1 (fp16), direct agg -> A1h ----
    ew1_kernel<<<(NUM_LABELS + 63) / 64, NT, 0, stream>>>(emb, W1, EW1h);
    agg1_kernel<<<blkW, NT, 0, stream>>>(EW1h, labels, csr, off, dinv, b1, A1h, N_NODES);

    // ---- conv2: aggregate A1h -> bufH, GEMM -> A2 ----
    agg2_kernel<<<blkW, NT, 0, stream>>>(A1h, csr, off, dinv, bufH, N_NODES);
    gemm2_kernel<<<blkG, NT, 0, stream>>>(bufH, W2, b2, A2, N_NODES);

    // ---- fused mean-pool + head ----
    pool_head_kernel<<<NUM_GRAPHS, NT, 0, stream>>>(A2, batch, W3, b3, W4, b4, out);
}

// Round 8
// 346.322 us; speedup vs baseline: 1.1960x; 1.1960x over previous
//
#include <hip/hip_runtime.h>
#include <hip/hip_fp16.h>

#define N_NODES    100000
#define N_EDGES    3200000
#define HIDDEN     64
#define NUM_GRAPHS 128
#define NUM_LABELS 1000

#define BKT_SHIFT  8
#define NPB        256                              // nodes per bucket
#define NBKT       ((N_NODES + NPB - 1) / NPB)      // 391
#define ENTCAP     8960                             // LDS staging capacity (71.7 KB)
#define BSLOT      ENTCAP                           // fixed bucket slot capacity
                                                    // mean bucket = 8192, sd = 90.4 -> 8960 is +8.5 sigma
#define SCHUNK     4096                             // edges per scatter block
#define SNBLK      ((N_EDGES + SCHUNK - 1) / SCHUNK)  // 782
#define CPT        ((SNBLK + 255) / 256)            // 4 blocks per thread in column scan

// ---------------- K1: per-block bucket histogram -> cnt[blk][NBKT] ----------------
__global__ __launch_bounds__(256) void hist_blk_kernel(
    const int* __restrict__ dst, int* __restrict__ cnt, int E) {
    __shared__ int h[NBKT];
    int t = threadIdx.x;
    for (int b = t; b < NBKT; b += 256) h[b] = 0;
    __syncthreads();
    int base = blockIdx.x * SCHUNK;
    int end  = min(base + SCHUNK, E);
    for (int i = base + t; i < end; i += 256)
        atomicAdd(&h[dst[i] >> BKT_SHIFT], 1);
    __syncthreads();
    int* o = cnt + (size_t)blockIdx.x * NBKT;
    for (int b = t; b < NBKT; b += 256) o[b] = h[b];
}

// ---------------- K2: per-bucket exclusive scan over blocks ----------------
// basem[blk][b] = sum_{blk'<blk} cnt[blk'][b];  bktTot[b] = total.
__global__ __launch_bounds__(256) void scan_cols_kernel(
    const int* __restrict__ cnt, int* __restrict__ basem, int* __restrict__ bktTot) {
    __shared__ int a[256], bsh[256];
    int b = blockIdx.x;
    int t = threadIdx.x;
    int v[CPT];
    int loc = 0;
    int blk0 = t * CPT;
    #pragma unroll
    for (int j = 0; j < CPT; ++j) {
        int blk = blk0 + j;
        int c = (blk < SNBLK) ? cnt[(size_t)blk * NBKT + b] : 0;
        v[j] = loc;                       // local exclusive prefix
        loc += c;
    }
    a[t] = loc; __syncthreads();
    int* pa = a; int* pb = bsh;
    #pragma unroll
    for (int d = 1; d < 256; d <<= 1) {
        int x = pa[t];
        if (t >= d) x += pa[t - d];
        pb[t] = x; __syncthreads();
        int* tmp = pa; pa = pb; pb = tmp;
    }
    int ex = (t == 0) ? 0 : pa[t - 1];
    #pragma unroll
    for (int j = 0; j < CPT; ++j) {
        int blk = blk0 + j;
        if (blk < SNBLK) basem[(size_t)blk * NBKT + b] = ex + v[j];
    }
    if (t == 255) bktTot[b] = pa[255];
}

// ---------------- K3: scan bucket totals -> dense offsets ----------------
__global__ __launch_bounds__(512) void scan_buckets_kernel(const int* __restrict__ bktTot,
                                                           int* __restrict__ boff) {
    __shared__ int a[512], b[512];
    int t = threadIdx.x;
    int v = (t < NBKT) ? bktTot[t] : 0;
    a[t] = v; __syncthreads();
    int* pa = a; int* pb = b;
    #pragma unroll
    for (int d = 1; d < 512; d <<= 1) {
        int x = pa[t];
        if (t >= d) x += pa[t - d];
        pb[t] = x; __syncthreads();
        int* tmp = pa; pa = pb; pb = tmp;
    }
    int ex = (t == 0) ? 0 : pa[t - 1];
    if (t < NBKT) boff[t] = ex;
    if (t == NBKT - 1) boff[NBKT] = pa[t];
}

// ---------------- K4: LDS-staged scatter (no global atomics, coalesced runs) ----------------
// barr entry: x = src | (dstoff << 20), y = bits(ew)
__global__ __launch_bounds__(256) void scatter_kernel(
    const int* __restrict__ src, const int* __restrict__ dst,
    const float* __restrict__ ew, const int* __restrict__ cnt,
    const int* __restrict__ basem, int2* __restrict__ barr, int E) {
    __shared__ int2 ent[SCHUNK];      // 32 KB: bucket-grouped entries
    __shared__ int  gaddr[SCHUNK];    // 16 KB: final slot per staged entry
    __shared__ int  h[NBKT];          // running cursor per bucket
    __shared__ int  ls[NBKT];         // local bucket start
    __shared__ int  a[256], bsc[256];
    int t = threadIdx.x;
    int blk = blockIdx.x;
    const int* cn = cnt   + (size_t)blk * NBKT;
    const int* bm = basem + (size_t)blk * NBKT;
    int i0 = 2 * t, i1 = 2 * t + 1;
    int c0 = (i0 < NBKT) ? cn[i0] : 0;
    int c1 = (i1 < NBKT) ? cn[i1] : 0;
    a[t] = c0 + c1; __syncthreads();
    int* pa = a; int* pb = bsc;
    #pragma unroll
    for (int d = 1; d < 256; d <<= 1) {
        int x = pa[t];
        if (t >= d) x += pa[t - d];
        pb[t] = x; __syncthreads();
        int* tmp = pa; pa = pb; pb = tmp;
    }
    int ex = (t == 0) ? 0 : pa[t - 1];
    if (i0 < NBKT) { ls[i0] = ex;      h[i0] = 0; }
    if (i1 < NBKT) { ls[i1] = ex + c0; h[i1] = 0; }
    __syncthreads();
    int base = blk * SCHUNK;
    int end  = min(base + SCHUNK, E);
    int m    = end - base;
    for (int i = base + t; i < end; i += 256) {
        int d  = dst[i];
        int bk = d >> BKT_SHIFT;
        int p  = atomicAdd(&h[bk], 1);
        int j  = ls[bk] + p;
        ent[j]   = make_int2(src[i] | ((d & (NPB - 1)) << 20), __float_as_int(ew[i]));
        gaddr[j] = bk * BSLOT + bm[bk] + p;
    }
    __syncthreads();
    for (int j = t; j < m; j += 256) barr[gaddr[j]] = ent[j];
}

// ---------------- K5: merged per-bucket finalize -> off + dinv + CSR (single barr read) ----
// csr entry: x = src | (labels[src] << 17), y = bits(ew * dinv[dst])   [dinv[src] NOT folded]
__global__ __launch_bounds__(256) void finalize_kernel(
    const int2* __restrict__ barr, const int* __restrict__ boff,
    const int* __restrict__ labels,
    int2* __restrict__ csr, int* __restrict__ off, float* __restrict__ dinv) {
    __shared__ int2  ent[ENTCAP];
    __shared__ int   hcnt[NPB];
    __shared__ float wsum[NPB];
    __shared__ float ldv[NPB];
    __shared__ int   ha[NPB], hcur[NPB];
    int b = blockIdx.x;
    int t = threadIdx.x;
    int s = boff[b], e = boff[b + 1];
    int m = e - s;
    const int2* bsrc = barr + (size_t)b * BSLOT;
    int node0 = b << BKT_SHIFT;
    int nn = min(NPB, N_NODES - node0);
    hcnt[t] = 0; wsum[t] = 0.f;
    __syncthreads();
    bool staged = (m <= ENTCAP);      // always true by construction
    for (int i = t; i < m; i += 256) {
        int2 v = bsrc[i];
        if (staged) ent[i] = v;
        int doff = (v.x >> 20) & (NPB - 1);
        atomicAdd(&hcnt[doff], 1);
        atomicAdd(&wsum[doff], __int_as_float(v.y));
    }
    __syncthreads();
    ha[t] = hcnt[t];
    __syncthreads();
    #pragma unroll
    for (int d = 1; d < NPB; d <<= 1) {
        int x = ha[t];
        if (t >= d) x += ha[t - d];
        __syncthreads();
        ha[t] = x;
        __syncthreads();
    }
    {
        int ex = (t == 0) ? 0 : ha[t - 1];
        hcur[t] = s + ex;
        float dv = rsqrtf(wsum[t] + 1.0f);
        ldv[t] = dv;
        if (t < nn) {
            off[node0 + t]  = s + ex;
            dinv[node0 + t] = dv;
        }
    }
    if (b == NBKT - 1 && t == 0) off[N_NODES] = e;
    __syncthreads();
    for (int i = t; i < m; i += 256) {
        int2 v = staged ? ent[i] : bsrc[i];
        int doff = (v.x >> 20) & (NPB - 1);
        int sv   = v.x & 0xFFFFF;                      // src (17 bits used)
        float wf = __int_as_float(v.y) * ldv[doff];    // dinv[dst] folded
        int lab  = labels[sv];
        int p = atomicAdd(&hcur[doff], 1);
        csr[p] = make_int2(sv | (lab << 17), __float_as_int(wf));
    }
}

// ---------------- EW1 = emb @ W1 (1000x64), fp16 out ----------------
__global__ __launch_bounds__(256) void ew1_kernel(
    const float* __restrict__ emb, const float* __restrict__ W,
    __half* __restrict__ OUTH) {
    __shared__ float Ws[64 * 64];
    __shared__ float Xs[64 * 65];
    int t = threadIdx.x;
    #pragma unroll
    for (int s = 0; s < 16; ++s) Ws[s * 256 + t] = W[s * 256 + t];
    int r0   = blockIdx.x * 64;
    int lrow = t >> 2;
    int c0   = (t & 3) * 16;
    int grow = r0 + lrow;
    const float* srcrow = (grow < NUM_LABELS) ? (emb + (size_t)grow * HIDDEN) : emb;
    #pragma unroll
    for (int c = 0; c < 16; c += 4) {
        float4 v = *(const float4*)(srcrow + c0 + c);
        Xs[lrow * 65 + c0 + c + 0] = v.x;
        Xs[lrow * 65 + c0 + c + 1] = v.y;
        Xs[lrow * 65 + c0 + c + 2] = v.z;
        Xs[lrow * 65 + c0 + c + 3] = v.w;
    }
    __syncthreads();
    int row = t & 63;
    int j0  = (t >> 6) * 16;
    float4 a0 = make_float4(0,0,0,0), a1 = a0, a2 = a0, a3 = a0;
    #pragma unroll
    for (int k = 0; k < 64; ++k) {
        float xv = Xs[row * 65 + k];
        const float4* wr = (const float4*)(Ws + k * 64 + j0);
        float4 w0 = wr[0], w1 = wr[1], w2 = wr[2], w3 = wr[3];
        a0.x = fmaf(xv, w0.x, a0.x); a0.y = fmaf(xv, w0.y, a0.y);
        a0.z = fmaf(xv, w0.z, a0.z); a0.w = fmaf(xv, w0.w, a0.w);
        a1.x = fmaf(xv, w1.x, a1.x); a1.y = fmaf(xv, w1.y, a1.y);
        a1.z = fmaf(xv, w1.z, a1.z); a1.w = fmaf(xv, w1.w, a1.w);
        a2.x = fmaf(xv, w2.x, a2.x); a2.y = fmaf(xv, w2.y, a2.y);
        a2.z = fmaf(xv, w2.z, a2.z); a2.w = fmaf(xv, w2.w, a2.w);
        a3.x = fmaf(xv, w3.x, a3.x); a3.y = fmaf(xv, w3.y, a3.y);
        a3.z = fmaf(xv, w3.z, a3.z); a3.w = fmaf(xv, w3.w, a3.w);
    }
    int gr = r0 + row;
    if (gr < NUM_LABELS) {
        union { __half2 h2[8]; uint4 u4[2]; } pk;
        pk.h2[0] = __floats2half2_rn(a0.x, a0.y);
        pk.h2[1] = __floats2half2_rn(a0.z, a0.w);
        pk.h2[2] = __floats2half2_rn(a1.x, a1.y);
        pk.h2[3] = __floats2half2_rn(a1.z, a1.w);
        pk.h2[4] = __floats2half2_rn(a2.x, a2.y);
        pk.h2[5] = __floats2half2_rn(a2.z, a2.w);
        pk.h2[6] = __floats2half2_rn(a3.x, a3.y);
        pk.h2[7] = __floats2half2_rn(a3.z, a3.w);
        uint4* o = (uint4*)(OUTH + (size_t)gr * HIDDEN + j0);
        o[0] = pk.u4[0]; o[1] = pk.u4[1];
    }
}

// 8 fp16 features -> fp32 acc, scalar weight.
// NOTE: macro params must not be named x/y/z/w (token-pasted into member access).
#define ACC8(rv_, wv_) { \
    const __half2* hp_ = (const __half2*)&(rv_); \
    float2 f0_ = __half22float2(hp_[0]); \
    float2 f1_ = __half22float2(hp_[1]); \
    float2 f2_ = __half22float2(hp_[2]); \
    float2 f3_ = __half22float2(hp_[3]); \
    accA.x = fmaf(f0_.x, (wv_), accA.x); accA.y = fmaf(f0_.y, (wv_), accA.y); \
    accA.z = fmaf(f1_.x, (wv_), accA.z); accA.w = fmaf(f1_.y, (wv_), accA.w); \
    accB.x = fmaf(f2_.x, (wv_), accB.x); accB.y = fmaf(f2_.y, (wv_), accB.y); \
    accB.z = fmaf(f3_.x, (wv_), accB.z); accB.w = fmaf(f3_.y, (wv_), accB.w); }

#define RED8(of_) { \
    accA.x += __shfl_xor(accA.x, of_, 64); accA.y += __shfl_xor(accA.y, of_, 64); \
    accA.z += __shfl_xor(accA.z, of_, 64); accA.w += __shfl_xor(accA.w, of_, 64); \
    accB.x += __shfl_xor(accB.x, of_, 64); accB.y += __shfl_xor(accB.y, of_, 64); \
    accB.z += __shfl_xor(accB.z, of_, 64); accB.w += __shfl_xor(accB.w, of_, 64); }

// ---------------- conv1: agg over EW1[label]; writes A1h PRE-SCALED by dinv[wid] ----------------
// wave per node; 8 lanes/edge; 4 independent edge-chains. w = csr.y * dinv[src].
__global__ __launch_bounds__(256) void agg1_kernel(
    const __half* __restrict__ EW1h, const int* __restrict__ labels,
    const int2* __restrict__ csr, const int* __restrict__ off,
    const float* __restrict__ dinv, const float* __restrict__ bias,
    __half* __restrict__ A1h, int n) {
    int wid  = (blockIdx.x * blockDim.x + threadIdx.x) >> 6;
    if (wid >= n) return;
    int lane = threadIdx.x & 63;
    int q = lane & 7, g = lane >> 3;
    int i   = off[wid] + g;
    int end = off[wid + 1];
    float4 accA = make_float4(0.f,0.f,0.f,0.f), accB = accA;
    while (i < end) {
        int2 e0 = csr[i];
        int2 e1 = (i + 8  < end) ? csr[i + 8]  : make_int2(0, 0);
        int2 e2 = (i + 16 < end) ? csr[i + 16] : make_int2(0, 0);
        int2 e3 = (i + 24 < end) ? csr[i + 24] : make_int2(0, 0);
        uint4 r0 = *(const uint4*)(EW1h + (size_t)((unsigned)e0.x >> 17) * HIDDEN + q * 8);
        uint4 r1 = *(const uint4*)(EW1h + (size_t)((unsigned)e1.x >> 17) * HIDDEN + q * 8);
        uint4 r2 = *(const uint4*)(EW1h + (size_t)((unsigned)e2.x >> 17) * HIDDEN + q * 8);
        uint4 r3 = *(const uint4*)(EW1h + (size_t)((unsigned)e3.x >> 17) * HIDDEN + q * 8);
        float w0 = __int_as_float(e0.y) * dinv[e0.x & 0x1FFFF];
        float w1 = __int_as_float(e1.y) * dinv[e1.x & 0x1FFFF];
        float w2 = __int_as_float(e2.y) * dinv[e2.x & 0x1FFFF];
        float w3 = __int_as_float(e3.y) * dinv[e3.x & 0x1FFFF];
        ACC8(r0, w0); ACC8(r1, w1); ACC8(r2, w2); ACC8(r3, w3);
        i += 32;
    }
    RED8(8); RED8(16); RED8(32);
    if (g == 0) {
        float di  = dinv[wid];
        float di2 = di * di;
        int labw = labels[wid];
        uint4 xu = *(const uint4*)(EW1h + (size_t)labw * HIDDEN + q * 8);
        const __half2* xp = (const __half2*)&xu;
        float2 x0 = __half22float2(xp[0]);
        float2 x1 = __half22float2(xp[1]);
        float2 x2 = __half22float2(xp[2]);
        float2 x3 = __half22float2(xp[3]);
        const float4* bp = (const float4*)(bias + q * 8);
        float4 bv0 = bp[0], bv1 = bp[1];
        float4 vA, vB;
        vA.x = fmaxf(fmaf(x0.x, di2, accA.x) + bv0.x, 0.f);
        vA.y = fmaxf(fmaf(x0.y, di2, accA.y) + bv0.y, 0.f);
        vA.z = fmaxf(fmaf(x1.x, di2, accA.z) + bv0.z, 0.f);
        vA.w = fmaxf(fmaf(x1.y, di2, accA.w) + bv0.w, 0.f);
        vB.x = fmaxf(fmaf(x2.x, di2, accB.x) + bv1.x, 0.f);
        vB.y = fmaxf(fmaf(x2.y, di2, accB.y) + bv1.y, 0.f);
        vB.z = fmaxf(fmaf(x3.x, di2, accB.z) + bv1.z, 0.f);
        vB.w = fmaxf(fmaf(x3.y, di2, accB.w) + bv1.w, 0.f);
        // pre-scale by dinv[wid]: A1h_scaled = di * A1   (agg2 then needs no dinv[src])
        union { __half2 h2[4]; uint4 u4; } pk;
        pk.h2[0] = __floats2half2_rn(di * vA.x, di * vA.y);
        pk.h2[1] = __floats2half2_rn(di * vA.z, di * vA.w);
        pk.h2[2] = __floats2half2_rn(di * vB.x, di * vB.y);
        pk.h2[3] = __floats2half2_rn(di * vB.z, di * vB.w);
        *(uint4*)(A1h + (size_t)wid * HIDDEN + q * 8) = pk.u4;
    }
}

// ---------------- conv2 pull aggregation (pre-scaled fp16 gather) -> fp32 out ----------------
// w = csr.y = ew*dinv[dst]; rows carry dinv[src]. Self term: di * A1h_scaled[wid] = di^2 * A1.
__global__ __launch_bounds__(256) void agg2_kernel(
    const __half* __restrict__ Xh,
    const int2* __restrict__ csr, const int* __restrict__ off,
    const float* __restrict__ dinv, float* __restrict__ OUT, int n) {
    int wid  = (blockIdx.x * blockDim.x + threadIdx.x) >> 6;
    if (wid >= n) return;
    int lane = threadIdx.x & 63;
    int q = lane & 7, g = lane >> 3;
    int i   = off[wid] + g;
    int end = off[wid + 1];
    float4 accA = make_float4(0.f,0.f,0.f,0.f), accB = accA;
    while (i < end) {
        int2 e0 = csr[i];
        int2 e1 = (i + 8  < end) ? csr[i + 8]  : make_int2(0, 0);
        int2 e2 = (i + 16 < end) ? csr[i + 16] : make_int2(0, 0);
        int2 e3 = (i + 24 < end) ? csr[i + 24] : make_int2(0, 0);
        uint4 r0 = *(const uint4*)(Xh + (size_t)(e0.x & 0x1FFFF) * HIDDEN + q * 8);
        uint4 r1 = *(const uint4*)(Xh + (size_t)(e1.x & 0x1FFFF) * HIDDEN + q * 8);
        uint4 r2 = *(const uint4*)(Xh + (size_t)(e2.x & 0x1FFFF) * HIDDEN + q * 8);
        uint4 r3 = *(const uint4*)(Xh + (size_t)(e3.x & 0x1FFFF) * HIDDEN + q * 8);
        float w0 = __int_as_float(e0.y);
        float w1 = __int_as_float(e1.y);
        float w2 = __int_as_float(e2.y);
        float w3 = __int_as_float(e3.y);
        ACC8(r0, w0); ACC8(r1, w1); ACC8(r2, w2); ACC8(r3, w3);
        i += 32;
    }
    RED8(8); RED8(16); RED8(32);
    if (g == 0) {
        float di  = dinv[wid];
        uint4 xu = *(const uint4*)(Xh + (size_t)wid * HIDDEN + q * 8);
        const __half2* xp = (const __half2*)&xu;
        float2 x0 = __half22float2(xp[0]);
        float2 x1 = __half22float2(xp[1]);
        float2 x2 = __half22float2(xp[2]);
        float2 x3 = __half22float2(xp[3]);
        accA.x = fmaf(x0.x, di, accA.x);
        accA.y = fmaf(x0.y, di, accA.y);
        accA.z = fmaf(x1.x, di, accA.z);
        accA.w = fmaf(x1.y, di, accA.w);
        accB.x = fmaf(x2.x, di, accB.x);
        accB.y = fmaf(x2.y, di, accB.y);
        accB.z = fmaf(x3.x, di, accB.z);
        accB.w = fmaf(x3.y, di, accB.w);
        float* o = OUT + (size_t)wid * HIDDEN + q * 8;
        *(float4*)o       = accA;
        *(float4*)(o + 4) = accB;
    }
}

// ---------------- GEMM + bias + relu -> fp16 out ----------------
__global__ __launch_bounds__(256) void gemm2_kernel(
    const float* __restrict__ X, const float* __restrict__ W,
    const float* __restrict__ bias, __half* __restrict__ OUT, int n) {
    __shared__ float Ws[64 * 64];
    __shared__ float Xs[64 * 65];
    int t = threadIdx.x;
    #pragma unroll
    for (int s = 0; s < 16; ++s) Ws[s * 256 + t] = W[s * 256 + t];
    int r0   = blockIdx.x * 64;
    int lrow = t >> 2;
    int c0   = (t & 3) * 16;
    const float* srcrow = ((r0 + lrow) < n) ? (X + (size_t)(r0 + lrow) * HIDDEN) : X;
    #pragma unroll
    for (int c = 0; c < 16; c += 4) {
        float4 v = *(const float4*)(srcrow + c0 + c);
        Xs[lrow * 65 + c0 + c + 0] = v.x;
        Xs[lrow * 65 + c0 + c + 1] = v.y;
        Xs[lrow * 65 + c0 + c + 2] = v.z;
        Xs[lrow * 65 + c0 + c + 3] = v.w;
    }
    __syncthreads();
    int row = t & 63;
    int j0  = (t >> 6) * 16;
    float4 a0 = *(const float4*)(bias + j0 + 0);
    float4 a1 = *(const float4*)(bias + j0 + 4);
    float4 a2 = *(const float4*)(bias + j0 + 8);
    float4 a3 = *(const float4*)(bias + j0 + 12);
    #pragma unroll
    for (int k = 0; k < 64; ++k) {
        float xv = Xs[row * 65 + k];
        const float4* wr = (const float4*)(Ws + k * 64 + j0);
        float4 w0 = wr[0], w1 = wr[1], w2 = wr[2], w3 = wr[3];
        a0.x = fmaf(xv, w0.x, a0.x); a0.y = fmaf(xv, w0.y, a0.y);
        a0.z = fmaf(xv, w0.z, a0.z); a0.w = fmaf(xv, w0.w, a0.w);
        a1.x = fmaf(xv, w1.x, a1.x); a1.y = fmaf(xv, w1.y, a1.y);
        a1.z = fmaf(xv, w1.z, a1.z); a1.w = fmaf(xv, w1.w, a1.w);
        a2.x = fmaf(xv, w2.x, a2.x); a2.y = fmaf(xv, w2.y, a2.y);
        a2.z = fmaf(xv, w2.z, a2.z); a2.w = fmaf(xv, w2.w, a2.w);
        a3.x = fmaf(xv, w3.x, a3.x); a3.y = fmaf(xv, w3.y, a3.y);
        a3.z = fmaf(xv, w3.z, a3.z); a3.w = fmaf(xv, w3.w, a3.w);
    }
    int gr = r0 + row;
    if (gr < n) {
        a0.x = fmaxf(a0.x, 0.f); a0.y = fmaxf(a0.y, 0.f); a0.z = fmaxf(a0.z, 0.f); a0.w = fmaxf(a0.w, 0.f);
        a1.x = fmaxf(a1.x, 0.f); a1.y = fmaxf(a1.y, 0.f); a1.z = fmaxf(a1.z, 0.f); a1.w = fmaxf(a1.w, 0.f);
        a2.x = fmaxf(a2.x, 0.f); a2.y = fmaxf(a2.y, 0.f); a2.z = fmaxf(a2.z, 0.f); a2.w = fmaxf(a2.w, 0.f);
        a3.x = fmaxf(a3.x, 0.f); a3.y = fmaxf(a3.y, 0.f); a3.z = fmaxf(a3.z, 0.f); a3.w = fmaxf(a3.w, 0.f);
        union { __half2 h2[8]; uint4 u4[2]; } pk;
        pk.h2[0] = __floats2half2_rn(a0.x, a0.y);
        pk.h2[1] = __floats2half2_rn(a0.z, a0.w);
        pk.h2[2] = __floats2half2_rn(a1.x, a1.y);
        pk.h2[3] = __floats2half2_rn(a1.z, a1.w);
        pk.h2[4] = __floats2half2_rn(a2.x, a2.y);
        pk.h2[5] = __floats2half2_rn(a2.z, a2.w);
        pk.h2[6] = __floats2half2_rn(a3.x, a3.y);
        pk.h2[7] = __floats2half2_rn(a3.z, a3.w);
        uint4* o = (uint4*)(OUT + (size_t)gr * HIDDEN + j0);
        o[0] = pk.u4[0]; o[1] = pk.u4[1];
    }
}

// ---------------- fused mean-pool (fp16 in, 1024 threads) + MLP head ----------------
__global__ __launch_bounds__(1024) void pool_head_kernel(
    const __half* __restrict__ A, const int* __restrict__ batch,
    const float* __restrict__ W3, const float* __restrict__ b3,
    const float* __restrict__ W4, const float* __restrict__ b4,
    float* __restrict__ out) {
    __shared__ int   sb[2];
    __shared__ float sd[16][64];
    __shared__ float gv[64];
    int gidx = blockIdx.x;
    int t = threadIdx.x;
    if (t < 2) {
        int target = gidx + t;
        int lo = 0, hi = N_NODES;
        while (lo < hi) {
            int mid = (lo + hi) >> 1;
            if (batch[mid] < target) lo = mid + 1; else hi = mid;
        }
        sb[t] = lo;
    }
    __syncthreads();
    int start = sb[0], end = sb[1];
    int col = t & 63, rg = t >> 6;            // 16 row-groups in flight
    float sum = 0.f;
    for (int r = start + rg; r < end; r += 16)
        sum += __half2float(A[(size_t)r * HIDDEN + col]);
    sd[rg][col] = sum;
    __syncthreads();
    if (t < 64) {
        float tot = 0.f;
        #pragma unroll
        for (int j = 0; j < 16; ++j) tot += sd[j][col];
        float cnt = (float)(end - start);
        gv[col] = tot / fmaxf(cnt, 1.0f);
    }
    __syncthreads();
    if (t < 64) {
        float acc = b3[t];
        #pragma unroll
        for (int k = 0; k < 64; ++k) acc = fmaf(gv[k], W3[k * 64 + t], acc);
        float p = fmaxf(acc, 0.f) * W4[t];
        #pragma unroll
        for (int o = 32; o > 0; o >>= 1) p += __shfl_down(p, o, 64);
        if (t == 0) out[gidx] = p + b4[0];
    }
}

extern "C" void kernel_launch(void* const* d_in, const int* in_sizes, int n_in,
                              void* d_out, int out_size, void* d_ws, size_t ws_size,
                              hipStream_t stream) {
    const int*   labels = (const int*)d_in[0];
    const int*   ei     = (const int*)d_in[1];
    const int*   src    = ei;
    const int*   dst    = ei + N_EDGES;
    const float* ew     = (const float*)d_in[2];
    const int*   batch  = (const int*)d_in[3];
    const float* emb    = (const float*)d_in[4];
    const float* W1 = (const float*)d_in[5],  *b1 = (const float*)d_in[6];
    const float* W2 = (const float*)d_in[7],  *b2 = (const float*)d_in[8];
    const float* W3 = (const float*)d_in[9],  *b3 = (const float*)d_in[10];
    const float* W4 = (const float*)d_in[11], *b4 = (const float*)d_in[12];
    float* out = (float*)d_out;

    // workspace carve
    float* ws   = (float*)d_ws;
    float* bufH = ws;                                       // N*64 fp32 (agg2 out / gemm2 in)
    float* bufA = bufH + (size_t)N_NODES * HIDDEN;          // N*64 region: A1h (fp16) -> A2h (fp16)
    int2*  csr  = (int2*)(bufA + (size_t)N_NODES * HIDDEN); // E int2
    int*   boff   = (int*)(csr + N_EDGES);                  // NBKT+1
    int*   bktTot = boff + NBKT + 1;                        // NBKT (bucket totals from scan_cols)
    int*   off    = bktTot + NBKT;                          // N+1
    float* dinv   = (float*)(off + N_NODES + 1);            // N
    __half* EW1h  = (__half*)(dinv + N_NODES);              // 1000*64 fp16
    // barr: fixed-slot bucket buffer, 391*8960*8B = 28.0 MB.
    // Aliases bufH (25.6 MB) + first 2.4 MB of bufA — both dead until after finalize.
    int2*  barr   = (int2*)ws;
    __half* A1h   = (__half*)bufA;                          // fp16 activation (pre-scaled by dinv)
    __half* A2h   = (__half*)bufA;                          // fp16 conv2+gemm2 out (A1h dead after agg2)
    // cnt/basem alias the csr region (dead before finalize writes csr).
    int*   cnt    = (int*)csr;                              // SNBLK*NBKT
    int*   basem  = cnt + (size_t)SNBLK * NBKT;             // SNBLK*NBKT

    const int NT = 256;
    const int blkW = (N_NODES * 64 + NT - 1) / NT;          // wave per node
    const int blkG = (N_NODES + 63) / 64;

    // ---- CSR build: radix-partition, zero global atomics, LDS-staged writeout ----
    hist_blk_kernel<<<SNBLK, NT, 0, stream>>>(dst, cnt, N_EDGES);
    scan_cols_kernel<<<NBKT, NT, 0, stream>>>(cnt, basem, bktTot);
    scan_buckets_kernel<<<1, 512, 0, stream>>>(bktTot, boff);
    scatter_kernel<<<SNBLK, NT, 0, stream>>>(src, dst, ew, cnt, basem, barr, N_EDGES);
    finalize_kernel<<<NBKT, NT, 0, stream>>>(barr, boff, labels, csr, off, dinv);

    // ---- conv1: EW1 = emb@W1 (fp16), direct agg -> A1h (pre-scaled) ----
    ew1_kernel<<<(NUM_LABELS + 63) / 64, NT, 0, stream>>>(emb, W1, EW1h);
    agg1_kernel<<<blkW, NT, 0, stream>>>(EW1h, labels, csr, off, dinv, b1, A1h, N_NODES);

    // ---- conv2: aggregate A1h -> bufH, GEMM -> A2h (fp16) ----
    agg2_kernel<<<blkW, NT, 0, stream>>>(A1h, csr, off, dinv, bufH, N_NODES);
    gemm2_kernel<<<blkG, NT, 0, stream>>>(bufH, W2, b2, A2h, N_NODES);

    // ---- fused mean-pool + head ----
    pool_head_kernel<<<NUM_GRAPHS, 1024, 0, stream>>>(A2h, batch, W3, b3, W4, b4, out);
}